// Round 17
// baseline (82.958 us; speedup 1.0000x reference)
//
#include <hip/hip_runtime.h>
#include <hip/hip_fp16.h>

typedef _Float16 half8 __attribute__((ext_vector_type(8)));
typedef _Float16 half2v __attribute__((ext_vector_type(2)));
typedef float f32x16 __attribute__((ext_vector_type(16)));
typedef float f32x4v __attribute__((ext_vector_type(4)));

#define MFMA16(A, B, C) __builtin_amdgcn_mfma_f32_32x32x16_f16((A), (B), (C), 0, 0, 0)

__device__ __forceinline__ f32x16 fzero16() {
  f32x16 z;
#pragma unroll
  for (int i = 0; i < 16; ++i) z[i] = 0.0f;
  return z;
}

__device__ __forceinline__ float max16(float vm, const f32x16& s) {
  const float g1 = fmaxf(fmaxf(s[0], s[1]), s[2]);
  const float g2 = fmaxf(fmaxf(s[3], s[4]), s[5]);
  const float g3 = fmaxf(fmaxf(s[6], s[7]), s[8]);
  const float g4 = fmaxf(fmaxf(s[9], s[10]), s[11]);
  const float g5 = fmaxf(fmaxf(s[12], s[13]), s[14]);
  const float h1 = fmaxf(fmaxf(g1, g2), g3);
  const float h2 = fmaxf(fmaxf(g4, g5), s[15]);
  return fmaxf(fmaxf(vm, h1), h2);
}

// ---------------------------------------------------------------------------
// wprep v3: plain-fp16 weights in MFMA-fragment layout; 40 blocks. (kept)
// ---------------------------------------------------------------------------
__global__ __launch_bounds__(256) void wprep_kernel(
    const float* __restrict__ w1, const float* __restrict__ w2,
    const float* __restrict__ w3,
    _Float16* __restrict__ w1p, _Float16* __restrict__ w2p,
    _Float16* __restrict__ w3p)
{
  const int t = threadIdx.x;
  const int blk = blockIdx.x;
  if (blk < 32) {
    const int cot = blk >> 2, sub = blk & 3;
    for (int e = sub * 2048 + t; e < sub * 2048 + 2048; e += 256) {
      const int j = e & 7, l = (e >> 3) & 63, cs = e >> 9;
      const int lr = l & 31, h = l >> 5;
      const int row = cot * 32 + lr;
      const int col = cs * 16 + 4 * h + (j & 3) + 8 * (j >> 2);
      w3p[((cot * 16 + cs) * 64 + l) * 8 + j] = (_Float16)w3[row * 256 + col];
    }
  } else {
    const int sub = blk - 32;   // 0..7
    for (int e = sub * 1024 + t; e < sub * 1024 + 1024; e += 256) {
      const int j = e & 7, l = (e >> 3) & 63, cs = e >> 9;
      const int lr = l & 31, h = l >> 5;
      const int col = cs * 16 + 4 * h + (j & 3) + 8 * (j >> 2);
      const int idx = (cs * 64 + l) * 8 + j;
      w1p[idx] = (_Float16)w1[lr * 256 + col];
      w2p[idx] = (_Float16)w2[lr * 256 + col];
    }
  }
}

// ---------------------------------------------------------------------------
// FUSED qkv projection v3 — plain fp16. (kept)
// ---------------------------------------------------------------------------
__global__ __launch_bounds__(256) void qkv_proj_kernel(
    const float* __restrict__ x,
    const _Float16* __restrict__ w1p, const float* __restrict__ b1,
    const _Float16* __restrict__ w2p, const float* __restrict__ b2,
    const _Float16* __restrict__ w3p, const float* __restrict__ b3,
    _Float16* __restrict__ qb, _Float16* __restrict__ kb,
    _Float16* __restrict__ vb)
{
  __shared__ f32x4v red[4][2][4][64];   // [wave][q/k][i4][lane], 32 KB
  const int t = threadIdx.x, w = t >> 6, l = t & 63;
  const int lr = l & 31, h = l >> 5;
  const int b = blockIdx.x >> 7;
  const int nt = blockIdx.x & 127;
  const float* xb = x + (size_t)b * 256 * 4096 + nt * 32 + lr;
  const int cot0 = w * 2, cot1 = w * 2 + 1;

  f32x16 accq = fzero16(), acck = fzero16();
  f32x16 accv0 = fzero16(), accv1 = fzero16();

  for (int cs = 0; cs < 16; ++cs) {
    const int c0 = cs * 16 + 4 * h;
    half8 xh;
#pragma unroll
    for (int j = 0; j < 8; ++j) {
      const int c = c0 + (j & 3) + 8 * (j >> 2);
      xh[j] = (_Float16)xb[(size_t)c * 4096];
    }
    const half8 wh0 = *(const half8*)&w3p[((cot0 * 16 + cs) * 64 + l) * 8];
    const half8 wh1 = *(const half8*)&w3p[((cot1 * 16 + cs) * 64 + l) * 8];
    accv0 = MFMA16(xh, wh0, accv0);
    accv1 = MFMA16(xh, wh1, accv1);
    if ((cs >> 2) == w) {
      const half8 w1h = *(const half8*)&w1p[(cs * 64 + l) * 8];
      const half8 w2h = *(const half8*)&w2p[(cs * 64 + l) * 8];
      accq = MFMA16(w1h, xh, accq);
      acck = MFMA16(w2h, xh, acck);
    }
  }

  const float bv0 = b3[cot0 * 32 + lr];
  const float bv1 = b3[cot1 * 32 + lr];
#pragma unroll
  for (int hfq = 0; hfq < 2; ++hfq) {
    half8 p0, p1;
#pragma unroll
    for (int j = 0; j < 8; ++j) {
      p0[j] = (_Float16)(accv0[8 * hfq + j] + bv0);
      p1[j] = (_Float16)(accv1[8 * hfq + j] + bv1);
    }
    const int ms = nt * 2 + hfq;
    *(half8*)&vb[((((size_t)b * 256 + ms) * 8 + cot0) * 64 + l) * 8] = p0;
    *(half8*)&vb[((((size_t)b * 256 + ms) * 8 + cot1) * 64 + l) * 8] = p1;
  }

#pragma unroll
  for (int i4 = 0; i4 < 4; ++i4) {
    f32x4v q4, k4;
#pragma unroll
    for (int c = 0; c < 4; ++c) { q4[c] = accq[4 * i4 + c]; k4[c] = acck[4 * i4 + c]; }
    red[w][0][i4][l] = q4;
    red[w][1][i4][l] = k4;
  }
  __syncthreads();
  if (w < 2) {
    _Float16* dst = (w == 0) ? qb : kb;
    const float* bias = (w == 0) ? b1 : b2;
    f32x16 tot;
#pragma unroll
    for (int i4 = 0; i4 < 4; ++i4) {
      f32x4v v = red[0][w][i4][l];
      v += red[1][w][i4][l];
      v += red[2][w][i4][l];
      v += red[3][w][i4][l];
#pragma unroll
      for (int c = 0; c < 4; ++c) tot[4 * i4 + c] = v[c];
    }
#pragma unroll
    for (int ds = 0; ds < 2; ++ds) {
      half8 ph;
#pragma unroll
      for (int j = 0; j < 8; ++j) {
        const int d = 16 * ds + 4 * h + (j & 3) + 8 * (j >> 2);
        ph[j] = (_Float16)(tot[8 * ds + j] + bias[d]);
      }
      *(half8*)&dst[((((size_t)b * 128 + nt) * 2 + ds) * 64 + l) * 8] = ph;
    }
  }
}

// ---------------------------------------------------------------------------
// attn v15: ROW-SPLIT co-residency. Block = 32 q-rows x 256 couts, 8 waves,
// grid 512 = 2 blocks/CU (4 waves/SIMD). Per 256-key period, wave w:
//   PRODUCE quarter w (2 QK MFMA + 16 exp, once — no duplication) -> Plds;
//   PVC cout-tile w: 2x(8 ds_read + 8 PV MFMA).
// One barrier/period; fused rowmax scan (32 MFMA/wave, K prefetch) with the
// SAME QK chain => exact max, P <= 1. VGPR capped 128 via launch_bounds(512,4).
// XCD swizzle: batch b -> XCDs {2b,2b+1}.
// ---------------------------------------------------------------------------
__global__ __launch_bounds__(512, 4) void attn_kernel(
    const _Float16* __restrict__ qb, const _Float16* __restrict__ kb,
    const _Float16* __restrict__ vb,
    const float* __restrict__ x, float* __restrict__ out)
{
  __shared__ __align__(16) _Float16 Plds[2][2][8][64][8];  // 32 KB
  __shared__ float Lred[8][32];
  const int t = threadIdx.x, w = t >> 6, l = t & 63;
  const int lr = l & 31, h = l >> 5;
  const int bid = blockIdx.x;
  const int xcd = bid & 7;
  const int b = xcd >> 1;
  const int rg = ((bid >> 3) << 1) | (xcd & 1);   // 32-row tile [0,128)
  const int ti = w >> 2;                           // produced sub-tile (128 keys)
  const int qq = w & 3;                            // quarter slot within sub-tile

  const _Float16* kbase = kb + (size_t)b * 131072 + (size_t)l * 8;
  const _Float16* vbase = vb + (size_t)b * 1048576 + (size_t)w * 512 + (size_t)l * 8;

// m = 32-key tile [0,128); P = 256-key period [0,16); ks = 16-key slot [0,8)
#define KFM(m, ds) (*(const half8*)(kbase + ((size_t)((m) * 2 + (ds))) * 512))
#define VF(P, TI, ks) (*(const half8*)(vbase + ((size_t)(16 * (P) + 8 * (TI) + (ks))) * 4096))

  const _Float16* qp = qb + (((size_t)b * 128 + rg) * 2 * 64 + l) * 8;
  const half8 qf0 = *(const half8*)qp;
  const half8 qf1 = *(const half8*)(qp + 512);
  const float LOG2E = 1.44269504088896340736f;

  f32x16 acc = fzero16();
  float Lacc = 0.f;
  half8 va0[8], va1[8];
  half8 kc0, kc1;

  // ---- V(period 0) issued FIRST: latency hides under the rowmax scan ----
#pragma unroll
  for (int ks = 0; ks < 8; ++ks) va0[ks] = VF(0, 0, ks);
#pragma unroll
  for (int ks = 0; ks < 8; ++ks) va1[ks] = VF(0, 1, ks);

  // ---- fused rowmax: wave w scans m in [16w, 16w+16), prefetch depth 1 ----
  {
    float vm = -3.0e38f;
    half8 sk0 = KFM(16 * w, 0), sk1 = KFM(16 * w, 1);
    for (int m = 16 * w; m < 16 * w + 16; ++m) {
      half8 nk0, nk1;
      if (m + 1 < 16 * w + 16) { nk0 = KFM(m + 1, 0); nk1 = KFM(m + 1, 1); }
      f32x16 s = fzero16();
      s = MFMA16(sk0, qf0, s);
      s = MFMA16(sk1, qf1, s);
      vm = max16(vm, s);
      sk0 = nk0; sk1 = nk1;
    }
    vm = fmaxf(vm, __shfl_xor(vm, 32));
    if (l < 32) Lred[w][lr] = vm;
  }
  __syncthreads();
  float Mr = Lred[0][lr];
#pragma unroll
  for (int ww = 1; ww < 8; ++ww) Mr = fmaxf(Mr, Lred[ww][lr]);
  const float nM2 = -Mr * LOG2E;

#define EXPPACK(S, BUF)                                                        \
  {                                                                            \
    float pvv[16];                                                             \
    float ls = 0.f;                                                            \
    _Pragma("unroll") for (int i = 0; i < 16; ++i) {                           \
      pvv[i] = exp2f(fmaf((S)[i], LOG2E, nM2)); ls += pvv[i];                  \
    }                                                                          \
    Lacc += ls;                                                                \
    union { half8 v; half2v h2[4]; } u0, u1;                                   \
    _Pragma("unroll") for (int jj = 0; jj < 4; ++jj) {                         \
      auto a0 = __builtin_amdgcn_cvt_pkrtz(pvv[2 * jj], pvv[2 * jj + 1]);      \
      auto a1 = __builtin_amdgcn_cvt_pkrtz(pvv[8 + 2 * jj], pvv[8 + 2 * jj + 1]); \
      u0.h2[jj] = *(half2v*)&a0;                                               \
      u1.h2[jj] = *(half2v*)&a1;                                               \
    }                                                                          \
    *(half8*)&Plds[BUF][ti][qq * 2 + 0][l][0] = u0.v;                          \
    *(half8*)&Plds[BUF][ti][qq * 2 + 1][l][0] = u1.v;                          \
  }

#define PVC(CB, TI, VA)                                                        \
  {                                                                            \
    __builtin_amdgcn_s_setprio(1);                                             \
    _Pragma("unroll") for (int ks = 0; ks < 8; ++ks) {                         \
      const half8 pb = *(const half8*)&Plds[CB][TI][ks][l][0];                 \
      acc = MFMA16(VA[ks], pb, acc);                                           \
    }                                                                          \
    __builtin_amdgcn_s_setprio(0);                                             \
  }

  // ---- prologue: produce period 0 -> buf0; prefetch K(period 1) ----
  kc0 = KFM(w, 0); kc1 = KFM(w, 1);
  {
    f32x16 s = fzero16();
    s = MFMA16(kc0, qf0, s);
    s = MFMA16(kc1, qf1, s);
    kc0 = KFM(8 + w, 0); kc1 = KFM(8 + w, 1);
    EXPPACK(s, 0)
  }
  asm volatile("s_waitcnt lgkmcnt(0)" ::: "memory");
  __builtin_amdgcn_s_barrier();
  asm volatile("" ::: "memory");

  // ---- 16 periods of 256 keys, ONE barrier each ----
  for (int P = 0; P < 16; ++P) {
    const int CB = P & 1, PB = CB ^ 1;

    if (P + 1 < 16) {
      f32x16 s = fzero16();
      s = MFMA16(kc0, qf0, s);
      s = MFMA16(kc1, qf1, s);
      if (P + 2 < 16) { kc0 = KFM(8 * (P + 2) + w, 0); kc1 = KFM(8 * (P + 2) + w, 1); }
      EXPPACK(s, PB)
    }
    PVC(CB, 0, va0)
    if (P + 1 < 16) {
#pragma unroll
      for (int ks = 0; ks < 8; ++ks) va0[ks] = VF(P + 1, 0, ks);
    }
    PVC(CB, 1, va1)
    if (P + 1 < 16) {
#pragma unroll
      for (int ks = 0; ks < 8; ++ks) va1[ks] = VF(P + 1, 1, ks);
    }

    asm volatile("s_waitcnt lgkmcnt(0)" ::: "memory");
    __builtin_amdgcn_s_barrier();
    asm volatile("" ::: "memory");
  }
#undef PVC
#undef EXPPACK
#undef KFM
#undef VF

  // ---- L reduce over 8 wave-partials ----
  {
    const float l2 = Lacc + __shfl_xor(Lacc, 32);
    if (l < 32) Lred[w][lr] = l2;
  }
  __syncthreads();
  float Ls = Lred[0][lr];
#pragma unroll
  for (int ww = 1; ww < 8; ++ww) Ls += Lred[ww][lr];
  const float invL = 1.0f / Ls;

  // ---- epilogue: normalize + residual ----
  const float* xb = x + (size_t)b * 1048576;
  float* ob = out + (size_t)b * 1048576;
  const int nn = rg * 32 + lr;
#pragma unroll
  for (int reg = 0; reg < 16; ++reg) {
    const int crel = (reg & 3) + 8 * (reg >> 2) + 4 * h;
    const int cout = w * 32 + crel;
    const size_t o = (size_t)cout * 4096 + nn;
    ob[o] = acc[reg] * invL + xb[o];
  }
}

extern "C" void kernel_launch(void* const* d_in, const int* in_sizes, int n_in,
                              void* d_out, int out_size, void* d_ws, size_t ws_size,
                              hipStream_t stream) {
  const float* x  = (const float*)d_in[0];
  const float* w1 = (const float*)d_in[1];
  const float* b1 = (const float*)d_in[2];
  const float* w2 = (const float*)d_in[3];
  const float* b2 = (const float*)d_in[4];
  const float* w3 = (const float*)d_in[5];
  const float* b3 = (const float*)d_in[6];
  float* out = (float*)d_out;

  char* ws = (char*)d_ws;
  _Float16* qb  = (_Float16*)(ws);                               // 1 MB
  _Float16* kb  = (_Float16*)(ws + (1u << 20));                  // 1 MB
  _Float16* vb  = (_Float16*)(ws + (2u << 20));                  // 8 MB
  _Float16* w1p = (_Float16*)(ws + (10u << 20) + (64u << 10));   // 16 KB
  _Float16* w2p = (_Float16*)(ws + (10u << 20) + (96u << 10));   // 16 KB
  _Float16* w3p = (_Float16*)(ws + (10u << 20) + (128u << 10));  // 128 KB

  hipLaunchKernelGGL(wprep_kernel, dim3(40), dim3(256), 0, stream,
                     w1, w2, w3, w1p, w2p, w3p);
  hipLaunchKernelGGL(qkv_proj_kernel, dim3(512), dim3(256), 0, stream,
                     x, w1p, b1, w2p, b2, w3p, b3, qb, kb, vb);
  hipLaunchKernelGGL(attn_kernel, dim3(512), dim3(512), 0, stream,
                     qb, kb, vb, x, out);
}